// Round 5
// baseline (100.629 us; speedup 1.0000x reference)
//
#include <hip/hip_runtime.h>

#define RNODES 1152
#define KDIM 9216                 // 1152*8
#define COUT 16
#define NCAPS 10
#define WSTRIDE (KDIM*COUT)       // 147456 floats per capsule

#define LROW 40                   // 32 k + 8 pad (ushorts) -> 80B rows
#define WBUF (NCAPS*COUT*LROW)    // 6400 ushorts = 12.8 KB per buffer
#define STEPS 6                   // k-steps of 32 per block
#define SPLITS 48                 // 48 * 6 * 32 = 9216 = KDIM
#define NBLK (SPLITS*4)           // 192 blocks
#define PARTL 10240               // per-block partial: 10 caps * 64 rows * 16
#define CNT_OFF ((size_t)NBLK * PARTL)   // 4 uint counters live after partials

using bf16x8 = __attribute__((ext_vector_type(8))) short;
using f32x4  = __attribute__((ext_vector_type(4))) float;

__device__ __forceinline__ unsigned short f2bf(float f) {
  unsigned int u = __builtin_bit_cast(unsigned int, f);
  u += 0x7FFFu + ((u >> 16) & 1u);   // round-to-nearest-even
  return (unsigned short)(u >> 16);
}

// ONE fused kernel, grid = 192. bid = mt*48 + ks: the 4 blocks sharing a
// W-slice (same ks, mt 0..3) are 48 apart -> same XCD (48 % 8 == 0) -> the
// W re-reads hit that XCD's L2 instead of going to L3/HBM 4x.
// Split-K fixup WITHOUT spinning (R3's agent-acquire spin storm killed BW):
// every block stores partials + threadfence + one atomicAdd on its mt counter;
// the last 10 arrivals each claim one capsule slice and reduce+squash it.
// Counter needs no init: ws poison 0xAAAAAAAA (or a zeroed first call) both
// decode via rel = old>=0xAAAAAAAA ? old-0xAAAAAAAA : old. Reduction order is
// a fixed loop -> bitwise-deterministic output regardless of arrival order.
__global__ __launch_bounds__(256, 1) void caps_fused(const float* __restrict__ x,
                                                     const float* __restrict__ W,
                                                     float* __restrict__ ws,
                                                     float* __restrict__ out) {
  __shared__ unsigned short wbuf[2][WBUF];   // ping-pong, 25.6 KB
  __shared__ unsigned int s_rel;
  const int tid = threadIdx.x;
  const int bid = blockIdx.x;
  const int mt  = bid / SPLITS;
  const int ks  = bid - mt * SPLITS;
  const int b0  = mt * 64;
  const int k0  = ks * (STEPS * 32);

  const int lane = tid & 63;
  const int wv   = tid >> 6;        // wave -> 16-row sub-tile
  const int q    = lane >> 4;       // k-quad
  const int m16  = lane & 15;

  const int c4 = tid >> 5;          // W decode: + 8*j
  const int kl = tid & 31;
  const float* xrow = x + (size_t)(b0 + wv * 16 + m16) * KDIM + k0 + q * 8;

  // ---- issue ALL 42 float4 loads up front (launch_bounds(256,1) keeps them
  // in flight; R3 showed VGPR_Count=64 serializes this) ----
  float4 pw[STEPS][5];
  float4 pa[STEPS][2];
#pragma unroll
  for (int s = 0; s < STEPS; ++s) {
#pragma unroll
    for (int j = 0; j < 5; ++j) {
      const int cc = c4 + 8 * j;                 // 0..39
      const int n  = cc >> 2, o4 = (cc & 3) << 2;
      pw[s][j] = *(const float4*)(W + (size_t)n * WSTRIDE +
                                  (size_t)(k0 + s * 32 + kl) * COUT + o4);
    }
    pa[s][0] = *(const float4*)(xrow + s * 32);
    pa[s][1] = *(const float4*)(xrow + s * 32 + 4);
  }

  f32x4 acc[NCAPS];
#pragma unroll
  for (int i = 0; i < NCAPS; ++i) acc[i] = (f32x4){0.f, 0.f, 0.f, 0.f};

#pragma unroll
  for (int s = 0; s < STEPS; ++s) {
    unsigned short* b = &wbuf[s & 1][0];
#pragma unroll
    for (int j = 0; j < 5; ++j) {
      const int cc = c4 + 8 * j;
      const int n  = cc >> 2, o4 = (cc & 3) << 2;
      const int cb = (n * COUT + o4) * LROW + kl;
      b[cb + 0 * LROW] = f2bf(pw[s][j].x);
      b[cb + 1 * LROW] = f2bf(pw[s][j].y);
      b[cb + 2 * LROW] = f2bf(pw[s][j].z);
      b[cb + 3 * LROW] = f2bf(pw[s][j].w);
    }
    __syncthreads();

    bf16x8 a;
    a[0] = (short)f2bf(pa[s][0].x); a[1] = (short)f2bf(pa[s][0].y);
    a[2] = (short)f2bf(pa[s][0].z); a[3] = (short)f2bf(pa[s][0].w);
    a[4] = (short)f2bf(pa[s][1].x); a[5] = (short)f2bf(pa[s][1].y);
    a[6] = (short)f2bf(pa[s][1].z); a[7] = (short)f2bf(pa[s][1].w);
#pragma unroll
    for (int nt = 0; nt < NCAPS; ++nt) {
      bf16x8 bf = *(const bf16x8*)&b[(nt * COUT + m16) * LROW + q * 8];
      acc[nt] = __builtin_amdgcn_mfma_f32_16x16x32_bf16(a, bf, acc[nt], 0, 0, 0);
    }
  }

  // ---- partial store: P[bid][n][row64][o] ----
  float* P = ws + (size_t)bid * PARTL;
  const int br = wv * 16 + q * 4;   // + r  (C/D: col=lane&15, row=q*4+reg)
#pragma unroll
  for (int nt = 0; nt < NCAPS; ++nt)
#pragma unroll
    for (int r = 0; r < 4; ++r)
      P[nt * 1024 + (br + r) * COUT + m16] = acc[nt][r];

  // ---- arrive: release partials, bump the mt counter ----
  __threadfence();          // agent-scope release (writes back L2 -> visible cross-XCD)
  __syncthreads();
  if (tid == 0) {
    unsigned int* cnt = (unsigned int*)(ws + CNT_OFF);
    unsigned int old = atomicAdd(&cnt[mt], 1u);
    s_rel = (old >= 0xAAAAAAAAu) ? old - 0xAAAAAAAAu : old;
  }
  __syncthreads();
  const unsigned int rel = s_rel;
  if (rel < SPLITS - NCAPS) return;          // first 38 arrivals: done

  // ---- reducer role: claim capsule slice nt, reduce 48 splits + squash ----
  const int nt = (int)(rel - (SPLITS - NCAPS));   // 0..9, each claimed once
  __threadfence();          // acquire side: invalidate stale cached lines

  // thread t owns float4 slot t of this (mt, nt) slice: row = t>>2, o4 = t&3
  const size_t slot = (size_t)nt * 256 + tid;     // float4 index within P
  const float4* pbase = (const float4*)(ws + (size_t)mt * SPLITS * PARTL) + slot;
  float4 s0 = {0,0,0,0}, s1 = {0,0,0,0}, s2 = {0,0,0,0}, s3 = {0,0,0,0};
#pragma unroll
  for (int kk = 0; kk < SPLITS; kk += 4) {
    float4 a0 = pbase[(size_t)(kk + 0) * (PARTL / 4)];
    float4 a1 = pbase[(size_t)(kk + 1) * (PARTL / 4)];
    float4 a2 = pbase[(size_t)(kk + 2) * (PARTL / 4)];
    float4 a3 = pbase[(size_t)(kk + 3) * (PARTL / 4)];
    s0.x += a0.x; s0.y += a0.y; s0.z += a0.z; s0.w += a0.w;
    s1.x += a1.x; s1.y += a1.y; s1.z += a1.z; s1.w += a1.w;
    s2.x += a2.x; s2.y += a2.y; s2.z += a2.z; s2.w += a2.w;
    s3.x += a3.x; s3.y += a3.y; s3.z += a3.z; s3.w += a3.w;
  }
  const float inv = 1.0f / (float)RNODES;
  float4 s;
  s.x = ((s0.x + s1.x) + (s2.x + s3.x)) * inv;
  s.y = ((s0.y + s1.y) + (s2.y + s3.y)) * inv;
  s.z = ((s0.z + s1.z) + (s2.z + s3.z)) * inv;
  s.w = ((s0.w + s1.w) + (s2.w + s3.w)) * inv;

  float sq = s.x * s.x + s.y * s.y + s.z * s.z + s.w * s.w;
  sq += __shfl_xor(sq, 1);   // o-group of 16 spans 4 adjacent lanes (o4 = t&3)
  sq += __shfl_xor(sq, 2);
  const float g = sqrtf(sq) / (1.0f + sq);
  s.x *= g; s.y *= g; s.z *= g; s.w *= g;

  // out[n*4096 + mt*1024 + row*16 + o4*4] as float4
  float4* o = (float4*)out;
  o[(size_t)nt * 1024 + (size_t)mt * 256 + tid] = s;
}

extern "C" void kernel_launch(void* const* d_in, const int* in_sizes, int n_in,
                              void* d_out, int out_size, void* d_ws, size_t ws_size,
                              hipStream_t stream) {
  const float* x = (const float*)d_in[0];   // [256,1152,8] fp32
  const float* W = (const float*)d_in[1];   // [10,1152,8,16] fp32
  float* ws  = (float*)d_ws;                // 7.9 MB partials + 4 counters
  float* out = (float*)d_out;               // 40960 fp32

  caps_fused<<<dim3(NBLK), dim3(256), 0, stream>>>(x, W, ws, out);
}

// Round 6
// 71.393 us; speedup vs baseline: 1.4095x; 1.4095x over previous
//
#include <hip/hip_runtime.h>

#define RNODES 1152
#define KDIM 9216                 // 1152*8
#define COUT 16
#define NCAPS 10
#define WSTRIDE (KDIM*COUT)       // 147456 floats per capsule

#define LROW 40                   // 32 k + 8 pad (ushorts) -> 80B rows
#define WBUF (NCAPS*COUT*LROW)    // 6400 ushorts = 12.8 KB per buffer
#define STEPS 9                   // k-steps of 32 per block
#define SPLITS 32                 // 32 * 9 * 32 = 9216 = KDIM
#define NBLK 256                  // 8 M-tiles x 32 splits = 1 block/CU exactly
#define PARTL (32*COUT*NCAPS)     // 5120 floats per block partial (32 rows)
#define PARTL4 (PARTL/4)          // 1280 float4

using bf16x8 = __attribute__((ext_vector_type(8))) short;
using f32x4  = __attribute__((ext_vector_type(4))) float;

// round-to-nearest (ties up): 2 VALU ops vs 4 for full RNE; error <= 2^-9 rel, unbiased.
__device__ __forceinline__ unsigned short f2bf(float f) {
  unsigned int u = __builtin_bit_cast(unsigned int, f);
  return (unsigned short)((u + 0x8000u) >> 16);
}

// grid = 256 (one block per CU). bid = mt*32 + ks -> XCD = bid%8 = ks%8, so all
// 8 mt-blocks sharing W-slice ks sit on ONE XCD: W re-reads are L2 hits (8x reuse).
// Waves: pair p = wv>>1 owns rows p*16..p*16+15; half h = wv&1 owns capsules
// h*5..h*5+4 -> 5 MFMA per wave per step, balanced. Explicit depth-3 rotating
// prefetch (R3/R5 counters showed "load everything upfront" never materializes).
__global__ __launch_bounds__(256, 1) void caps_gemm(const float* __restrict__ x,
                                                    const float* __restrict__ W,
                                                    float* __restrict__ ws) {
  __shared__ unsigned short wbuf[2][WBUF];   // ping-pong, 25.6 KB
  const int tid = threadIdx.x;
  const int bid = blockIdx.x;
  const int mt  = bid >> 5;         // 0..7  (32-row M-tile)
  const int ks  = bid & 31;         // 0..31 (K split)
  const int b0  = mt * 32;
  const int k0  = ks * (STEPS * 32);   // 288-element K chunk

  const int lane = tid & 63;
  const int wv   = tid >> 6;
  const int p    = wv >> 1;         // row half
  const int h    = wv & 1;          // capsule half
  const int q    = lane >> 4;       // k-quad
  const int m16  = lane & 15;

  const int c4 = tid >> 5;          // W decode: col-quad = c4 + 8*j
  const int kl = tid & 31;

  const float* xrow = x + (size_t)(b0 + p * 16 + m16) * KDIM + k0 + q * 8;

  float4 pw[3][5];
  float4 pa[3][2];

  auto load_step = [&](int s, int slot) {
#pragma unroll
    for (int j = 0; j < 5; ++j) {
      const int cc = c4 + 8 * j;                 // 0..39 col-quads
      const int n  = cc >> 2, o4 = (cc & 3) << 2;
      pw[slot][j] = *(const float4*)(W + (size_t)n * WSTRIDE +
                                     (size_t)(k0 + s * 32 + kl) * COUT + o4);
    }
    pa[slot][0] = *(const float4*)(xrow + s * 32);
    pa[slot][1] = *(const float4*)(xrow + s * 32 + 4);
  };

  load_step(0, 0);
  load_step(1, 1);
  load_step(2, 2);

  f32x4 acc[5];
#pragma unroll
  for (int i = 0; i < 5; ++i) acc[i] = (f32x4){0.f, 0.f, 0.f, 0.f};

#pragma unroll
  for (int s = 0; s < STEPS; ++s) {
    const int slot = s % 3;
    unsigned short* b = &wbuf[s & 1][0];
    // stage W step s: [col][k] bf16 transpose
#pragma unroll
    for (int j = 0; j < 5; ++j) {
      const int cc = c4 + 8 * j;
      const int cb = cc * 4 * LROW + kl;
      b[cb + 0 * LROW] = f2bf(pw[slot][j].x);
      b[cb + 1 * LROW] = f2bf(pw[slot][j].y);
      b[cb + 2 * LROW] = f2bf(pw[slot][j].z);
      b[cb + 3 * LROW] = f2bf(pw[slot][j].w);
    }
    __syncthreads();
    // write(s+2) to this parity happens after barrier(s+1); reads(s) drain
    // before barrier(s+1) -> classic 2-buffer safety, 1 barrier/step.

    bf16x8 a;
    a[0] = (short)f2bf(pa[slot][0].x); a[1] = (short)f2bf(pa[slot][0].y);
    a[2] = (short)f2bf(pa[slot][0].z); a[3] = (short)f2bf(pa[slot][0].w);
    a[4] = (short)f2bf(pa[slot][1].x); a[5] = (short)f2bf(pa[slot][1].y);
    a[6] = (short)f2bf(pa[slot][1].z); a[7] = (short)f2bf(pa[slot][1].w);

    if (s + 3 < STEPS) load_step(s + 3, slot);   // slot just freed

#pragma unroll
    for (int j = 0; j < 5; ++j) {
      const int nt = h * 5 + j;
      bf16x8 bf = *(const bf16x8*)&b[(nt * COUT + m16) * LROW + q * 8];
      acc[j] = __builtin_amdgcn_mfma_f32_16x16x32_bf16(a, bf, acc[j], 0, 0, 0);
    }
  }

  // ---- partial store: P[bid][n][row32][o] ----
  float* P = ws + (size_t)bid * PARTL;
  const int prow = p * 16 + q * 4;   // C/D: col=lane&15 (=o), row=q*4+reg
#pragma unroll
  for (int j = 0; j < 5; ++j)
#pragma unroll
    for (int r = 0; r < 4; ++r)
      P[(h * 5 + j) * 512 + (prow + r) * COUT + m16] = acc[j][r];
}

// grid = 80 x 128: thread f owns output float4 f (f = n*1024 + b*4 + o4),
// sums 32 splits with fixed order (deterministic), squashes over 4-lane o-groups.
__global__ __launch_bounds__(128, 1) void caps_reduce(const float* __restrict__ ws,
                                                      float* __restrict__ out) {
  const int f  = blockIdx.x * 128 + threadIdx.x;   // 0..10239
  const int n  = f >> 10;
  const int b  = (f >> 2) & 255;
  const int o4 = f & 3;
  const int mt = b >> 5, row = b & 31;

  const float4* base = (const float4*)ws + (size_t)(mt * SPLITS) * PARTL4
                       + n * 128 + row * 4 + o4;
  float4 s0 = {0,0,0,0}, s1 = {0,0,0,0}, s2 = {0,0,0,0}, s3 = {0,0,0,0};
#pragma unroll
  for (int kk = 0; kk < SPLITS; kk += 4) {
    float4 a0 = base[(size_t)(kk + 0) * PARTL4];
    float4 a1 = base[(size_t)(kk + 1) * PARTL4];
    float4 a2 = base[(size_t)(kk + 2) * PARTL4];
    float4 a3 = base[(size_t)(kk + 3) * PARTL4];
    s0.x += a0.x; s0.y += a0.y; s0.z += a0.z; s0.w += a0.w;
    s1.x += a1.x; s1.y += a1.y; s1.z += a1.z; s1.w += a1.w;
    s2.x += a2.x; s2.y += a2.y; s2.z += a2.z; s2.w += a2.w;
    s3.x += a3.x; s3.y += a3.y; s3.z += a3.z; s3.w += a3.w;
  }
  const float inv = 1.0f / (float)RNODES;
  float4 s;
  s.x = ((s0.x + s1.x) + (s2.x + s3.x)) * inv;
  s.y = ((s0.y + s1.y) + (s2.y + s3.y)) * inv;
  s.z = ((s0.z + s1.z) + (s2.z + s3.z)) * inv;
  s.w = ((s0.w + s1.w) + (s2.w + s3.w)) * inv;

  float sq = s.x * s.x + s.y * s.y + s.z * s.z + s.w * s.w;
  sq += __shfl_xor(sq, 1);   // o-group of 16 = 4 adjacent lanes (o4 = f&3)
  sq += __shfl_xor(sq, 2);
  const float g = sqrtf(sq) / (1.0f + sq);
  s.x *= g; s.y *= g; s.z *= g; s.w *= g;

  ((float4*)out)[f] = s;     // out float4 index == f by construction
}

extern "C" void kernel_launch(void* const* d_in, const int* in_sizes, int n_in,
                              void* d_out, int out_size, void* d_ws, size_t ws_size,
                              hipStream_t stream) {
  const float* x = (const float*)d_in[0];   // [256,1152,8] fp32
  const float* W = (const float*)d_in[1];   // [10,1152,8,16] fp32
  float* ws  = (float*)d_ws;                // 256*5120 fp32 partials (5.2 MB)
  float* out = (float*)d_out;               // 40960 fp32

  caps_gemm<<<dim3(NBLK), dim3(256), 0, stream>>>(x, W, ws);
  caps_reduce<<<dim3(80), dim3(128), 0, stream>>>(ws, out);
}